// Round 18
// baseline (459.599 us; speedup 1.0000x reference)
//
#include <hip/hip_runtime.h>
#include <cstdint>
#include <cstddef>

// ---------------------------------------------------------------------------
// MaxKGIN. R18: r17 retry — the hi-LDS/lo-L2 GEMM had a units bug (WtL is
// short* but was indexed with the BYTE offset kb -> read at 2x offset).
// Fixed: lo fragments indexed with element offset c*32+kg*8. Design: W-hi in
// 34.8KB LDS (4 blocks/CU, 16 waves/CU), W-lo streamed from L2 per use.
// maxk v3, gather6, CSR two-level binning frozen from r15 (394us).
// ---------------------------------------------------------------------------

typedef __attribute__((ext_vector_type(8))) short bf16x8;
typedef __attribute__((ext_vector_type(4))) float f32x4;

#define BSHIFT 8
#define NBUK 512  // covers dst>>8 for n <= 131072

__device__ __forceinline__ unsigned rne_bf16(float v) {
  unsigned u = __float_as_uint(v);
  return (u + 0x7fffu + ((u >> 16) & 1u)) >> 16;
}

// ---------------- fused W^T build: all 4 weights -> hi/lo bf16 --------------
__global__ __launch_bounds__(256) void wt_build_all_kernel(
    const float* __restrict__ W_in, const float* __restrict__ W_lin,
    const float* __restrict__ W_out, short* __restrict__ out) {
  const int i = blockIdx.x * 256 + threadIdx.x;
  if (i >= 57344) return;
  const float* W;
  int nout, local;
  short* H;
  if (i < 16384) {
    W = W_in; nout = 128; local = i; H = out;
  } else if (i < 32768) {
    W = W_lin; nout = 128; local = i - 16384; H = out + 32768;
  } else if (i < 49152) {
    W = W_lin + 16384; nout = 128; local = i - 32768; H = out + 65536;
  } else {
    W = W_out; nout = 64; local = i - 49152; H = out + 98304;
  }
  const int nn = local >> 7, k = local & 127;
  const float v = W[k * nout + nn];
  const unsigned hb = rne_bf16(v);
  const float hf = __uint_as_float(hb << 16);
  const unsigned lb = rne_bf16(v - hf);
  H[local] = (short)hb;
  H[local + nout * 128] = (short)lb;
}

// ---------------- GEMM A (fp32 X): 256-row tiles, hi-LDS / lo-L2 ------------
__global__ __launch_bounds__(256, 2) void gemm_in_kernel(
    const float* __restrict__ X, const short* __restrict__ WtH,
    const short* __restrict__ WtL, const float* __restrict__ bias,
    short* __restrict__ Yh, short* __restrict__ Yl, int nrows, int ntiles) {
  constexpr int NOUT = 128;
  constexpr int NT = NOUT / 16;
  constexpr int LDB = 128 * 2 + 16;
  __shared__ char lds[NOUT * LDB];

  const int tid = threadIdx.x;
  for (int u = tid; u < NOUT * 16; u += 256) {
    const int nrow = u >> 4, seg = u & 15;
    const float4 d = *(const float4*)&WtH[nrow * 128 + seg * 8];
    *(float4*)&lds[nrow * LDB + seg * 16] = d;
  }
  __syncthreads();

  const int lane = tid & 63;
  const int wv = tid >> 6;
  const int li = lane & 15;
  const int kg = lane >> 4;

  float bv[NT];
#pragma unroll
  for (int t = 0; t < NT; ++t) bv[t] = bias[t * 16 + li];

  for (int tile = blockIdx.x; tile < ntiles; tile += gridDim.x) {
    const int rowbase = tile * 256 + wv * 64;

    f32x4 acc[4][NT];
#pragma unroll
    for (int rg = 0; rg < 4; ++rg)
#pragma unroll
      for (int t = 0; t < NT; ++t) acc[rg][t] = (f32x4){0.f, 0.f, 0.f, 0.f};

#pragma unroll
    for (int c = 0; c < 4; ++c) {
      bf16x8 ah[4], al[4];
#pragma unroll
      for (int rg = 0; rg < 4; ++rg) {
        const int row = rowbase + rg * 16 + li;
        const int rowc = (row < nrows) ? row : (nrows - 1);
        const float* xrow = X + (size_t)rowc * 128 + c * 32 + kg * 8;
        const float4 p0 = *(const float4*)&xrow[0];
        const float4 p1 = *(const float4*)&xrow[4];
        const float f[8] = {p0.x, p0.y, p0.z, p0.w, p1.x, p1.y, p1.z, p1.w};
#pragma unroll
        for (int e = 0; e < 8; ++e) {
          const unsigned hb = rne_bf16(f[e]);
          const float hf = __uint_as_float(hb << 16);
          ah[rg][e] = (short)hb;
          al[rg][e] = (short)rne_bf16(f[e] - hf);
        }
      }
      const int kb = c * 64 + kg * 16;   // byte offset (LDS)
      const int ke = c * 32 + kg * 8;    // element offset (global lo plane)
#pragma unroll
      for (int t = 0; t < NT; ++t) {
        const bf16x8 bh = *(const bf16x8*)&lds[(t * 16 + li) * LDB + kb];
        const bf16x8 bl = *(const bf16x8*)&WtL[(t * 16 + li) * 128 + ke];
#pragma unroll
        for (int rg = 0; rg < 4; ++rg) {
          acc[rg][t] =
              __builtin_amdgcn_mfma_f32_16x16x32_bf16(al[rg], bh, acc[rg][t], 0, 0, 0);
          acc[rg][t] =
              __builtin_amdgcn_mfma_f32_16x16x32_bf16(ah[rg], bl, acc[rg][t], 0, 0, 0);
          acc[rg][t] =
              __builtin_amdgcn_mfma_f32_16x16x32_bf16(ah[rg], bh, acc[rg][t], 0, 0, 0);
        }
      }
    }

#pragma unroll
    for (int rg = 0; rg < 4; ++rg) {
      const int orow = rowbase + rg * 16 + kg * 4;
#pragma unroll
      for (int t = 0; t < NT; ++t) {
        const int col = t * 16 + li;
#pragma unroll
        for (int r = 0; r < 4; ++r) {
          const int rr = orow + r;
          if (rr < nrows) {
            const float o = fmaxf(acc[rg][t][r] + bv[t], 0.f);
            const unsigned hb = rne_bf16(o);
            const float hf = __uint_as_float(hb << 16);
            Yh[(size_t)rr * 128 + col] = (short)hb;
            Yl[(size_t)rr * 128 + col] = (short)rne_bf16(o - hf);
          }
        }
      }
    }
  }
}

// ---------------- GEMM B (bf16-plane X): hi-LDS / lo-L2 ---------------------
template <int NOUT>
__global__ __launch_bounds__(256, 2) void gemm_pl_kernel(
    const short* __restrict__ Xh, const short* __restrict__ Xl,
    const short* __restrict__ WtH, const short* __restrict__ WtL,
    const float* __restrict__ bias, float* __restrict__ Y, int nrows,
    int ntiles) {
  constexpr int NT = NOUT / 16;
  constexpr int LDB = 128 * 2 + 16;
  __shared__ char lds[NOUT * LDB];

  const int tid = threadIdx.x;
  for (int u = tid; u < NOUT * 16; u += 256) {
    const int nrow = u >> 4, seg = u & 15;
    const float4 d = *(const float4*)&WtH[nrow * 128 + seg * 8];
    *(float4*)&lds[nrow * LDB + seg * 16] = d;
  }
  __syncthreads();

  const int lane = tid & 63;
  const int wv = tid >> 6;
  const int li = lane & 15;
  const int kg = lane >> 4;

  float bv[NT];
#pragma unroll
  for (int t = 0; t < NT; ++t) bv[t] = bias[t * 16 + li];

  for (int tile = blockIdx.x; tile < ntiles; tile += gridDim.x) {
    const int rowbase = tile * 256 + wv * 64;

    f32x4 acc[4][NT];
#pragma unroll
    for (int rg = 0; rg < 4; ++rg)
#pragma unroll
      for (int t = 0; t < NT; ++t) acc[rg][t] = (f32x4){0.f, 0.f, 0.f, 0.f};

#pragma unroll
    for (int c = 0; c < 4; ++c) {
      bf16x8 ah[4], al[4];
#pragma unroll
      for (int rg = 0; rg < 4; ++rg) {
        const int row = rowbase + rg * 16 + li;
        const int rowc = (row < nrows) ? row : (nrows - 1);
        ah[rg] = *(const bf16x8*)&Xh[(size_t)rowc * 128 + c * 32 + kg * 8];
        al[rg] = *(const bf16x8*)&Xl[(size_t)rowc * 128 + c * 32 + kg * 8];
      }
      const int kb = c * 64 + kg * 16;   // byte offset (LDS)
      const int ke = c * 32 + kg * 8;    // element offset (global lo plane)
#pragma unroll
      for (int t = 0; t < NT; ++t) {
        const bf16x8 bh = *(const bf16x8*)&lds[(t * 16 + li) * LDB + kb];
        const bf16x8 bl = *(const bf16x8*)&WtL[(t * 16 + li) * 128 + ke];
#pragma unroll
        for (int rg = 0; rg < 4; ++rg) {
          acc[rg][t] =
              __builtin_amdgcn_mfma_f32_16x16x32_bf16(al[rg], bh, acc[rg][t], 0, 0, 0);
          acc[rg][t] =
              __builtin_amdgcn_mfma_f32_16x16x32_bf16(ah[rg], bl, acc[rg][t], 0, 0, 0);
          acc[rg][t] =
              __builtin_amdgcn_mfma_f32_16x16x32_bf16(ah[rg], bh, acc[rg][t], 0, 0, 0);
        }
      }
    }

#pragma unroll
    for (int rg = 0; rg < 4; ++rg) {
      const int orow = rowbase + rg * 16 + kg * 4;
#pragma unroll
      for (int t = 0; t < NT; ++t) {
        const int col = t * 16 + li;
#pragma unroll
        for (int r = 0; r < 4; ++r) {
          const int rr = orow + r;
          if (rr < nrows) Y[(size_t)rr * NOUT + col] = acc[rg][t][r] + bv[t];
        }
      }
    }
  }
}

// ---------------- MaxK v3: 4 rows/wave, subgroup radix + early exit ---------
__global__ __launch_bounds__(256) void maxk_kernel(
    const float* __restrict__ T, unsigned char* __restrict__ Cs,
    float* __restrict__ Vs, int nrows) {
  const int lane = threadIdx.x & 63;
  const int wid = threadIdx.x >> 6;
  const int sub = lane >> 4;
  const int s = lane & 15;
  const int shift = sub * 16;
  const unsigned below = (1u << s) - 1u;
  const int nquads = (nrows + 3) / 4;

  for (int quad = blockIdx.x * 4 + wid; quad < nquads; quad += gridDim.x * 4) {
    const int row = quad * 4 + sub;
    const int rowc = (row < nrows) ? row : (nrows - 1);
    const float* Trow = T + (size_t)rowc * 128;

    float v[8];
    unsigned k[8];
#pragma unroll
    for (int j = 0; j < 8; ++j) {
      v[j] = Trow[j * 16 + s];
      const unsigned u = __float_as_uint(v[j]);
      k[j] = u ^ (((unsigned)((int)u >> 31)) | 0x80000000u);
    }

    unsigned P = 0;
    int kth = 16;
    int sz = 128;
    bool done = false;
    for (int b = 31; b >= 0; --b) {
      const unsigned tgt = (P >> b) | 1u;
      int c = 0;
#pragma unroll
      for (int j = 0; j < 8; ++j) {
        const unsigned long long bal = __ballot((k[j] >> b) == tgt);
        c += __popc((unsigned)((bal >> shift) & 0xFFFFull));
      }
      if (!done) {
        if (c >= kth) {
          P |= (1u << b);
          sz = c;
        } else {
          sz -= c;
          kth -= c;
        }
        done = (sz == kth);
      }
      if (__all(done)) break;
    }
    if (done) P -= 1u;  // select key >= old P; no ties remain

    unsigned gtm[8], eqm[8];
    int gt_total = 0;
#pragma unroll
    for (int j = 0; j < 8; ++j) {
      const unsigned long long gb = __ballot(k[j] > P);
      const unsigned long long eb = __ballot(k[j] == P);
      gtm[j] = (unsigned)((gb >> shift) & 0xFFFFull);
      eqm[j] = (unsigned)((eb >> shift) & 0xFFFFull);
      gt_total += __popc(gtm[j]);
    }
    const int need = 16 - gt_total;
    int gt_pre = 0, eq_pre = 0;
#pragma unroll
    for (int j = 0; j < 8; ++j) {
      const bool isgt = k[j] > P;
      const bool iseq = k[j] == P;
      const int gtb = gt_pre + __popc(gtm[j] & below);
      const int eqb = eq_pre + __popc(eqm[j] & below);
      if (row < nrows && (isgt || (iseq && eqb < need))) {
        const int rank = gtb + (isgt ? min(eqb, need) : eqb);
        Vs[(size_t)row * 16 + rank] = v[j];
        Cs[(size_t)row * 16 + rank] = (unsigned char)(j * 16 + s);
      }
      gt_pre += __popc(gtm[j]);
      eq_pre += __popc(eqm[j]);
    }
  }
}

// ---------------- CSR build v2: two-level binning ---------------------------
__global__ __launch_bounds__(256) void bhist_kernel(const int* __restrict__ dst,
                                                    int* __restrict__ BC,
                                                    int E) {
  __shared__ int bh[NBUK];
  for (int i = threadIdx.x; i < NBUK; i += 256) bh[i] = 0;
  __syncthreads();
  const int stride = gridDim.x * 256;
  for (int e = blockIdx.x * 256 + threadIdx.x; e < E; e += stride)
    atomicAdd(&bh[dst[e] >> BSHIFT], 1);
  __syncthreads();
  for (int i = threadIdx.x; i < NBUK; i += 256)
    if (bh[i]) atomicAdd(&BC[i], bh[i]);
}

__global__ __launch_bounds__(NBUK) void bscan_kernel(
    const int* __restrict__ BC, int* __restrict__ bases,
    int* __restrict__ bcur, int* __restrict__ rs, int n, int E) {
  __shared__ int sc[NBUK];
  const int t = threadIdx.x;
  const int c = BC[t];
  sc[t] = c;
  __syncthreads();
  for (int st = 1; st < NBUK; st <<= 1) {
    const int v = sc[t];
    const int u = (t >= st) ? sc[t - st] : 0;
    __syncthreads();
    sc[t] = v + u;
    __syncthreads();
  }
  const int excl = sc[t] - c;
  bases[t] = excl;
  bcur[t] = excl;
  if (t == 0) rs[n] = E;
}

__global__ __launch_bounds__(256) void bin_kernel(
    const int* __restrict__ src, const int* __restrict__ dst,
    int* __restrict__ bcur, uint2* __restrict__ binned, int E, int chunk) {
  __shared__ int cnt[NBUK], off[NBUK], gbase[NBUK];
  __shared__ unsigned short bktof[4096];
  __shared__ uint2 buf[4096];
  const int t = threadIdx.x;
  const int beg = blockIdx.x * chunk;
  const int m = min(chunk, E - beg);
  if (m <= 0) return;

  for (int i = t; i < NBUK; i += 256) cnt[i] = 0;
  __syncthreads();

  int d[16], s[16], lp[16], bk[16];
#pragma unroll
  for (int i = 0; i < 16; ++i) {
    const int j = i * 256 + t;
    if (j < m) {
      d[i] = dst[beg + j];
      s[i] = src[beg + j];
      bk[i] = d[i] >> BSHIFT;
      lp[i] = atomicAdd(&cnt[bk[i]], 1);
    } else {
      bk[i] = -1;
    }
  }
  __syncthreads();

  for (int i = t; i < NBUK; i += 256) off[i] = cnt[i];
  __syncthreads();
  for (int st = 1; st < NBUK; st <<= 1) {
    int v0, v1, u0, u1;
    {
      const int i0 = t, i1 = t + 256;
      v0 = off[i0]; u0 = (i0 >= st) ? off[i0 - st] : 0;
      v1 = off[i1]; u1 = (i1 >= st) ? off[i1 - st] : 0;
    }
    __syncthreads();
    off[t] = v0 + u0;
    off[t + 256] = v1 + u1;
    __syncthreads();
  }

  for (int i = t; i < NBUK; i += 256) {
    const int c = cnt[i];
    if (c > 0) {
      gbase[i] = atomicAdd(&bcur[i], c);
      const int e0 = off[i] - c;
      for (int k = 0; k < c; ++k) bktof[e0 + k] = (unsigned short)i;
    }
  }
  __syncthreads();

#pragma unroll
  for (int i = 0; i < 16; ++i) {
    if (bk[i] >= 0) {
      buf[(off[bk[i]] - cnt[bk[i]]) + lp[i]] =
          make_uint2((unsigned)d[i], (unsigned)s[i]);
    }
  }
  __syncthreads();

  for (int j = t; j < m; j += 256) {
    const int b = bktof[j];
    const int e0 = off[b] - cnt[b];
    binned[gbase[b] + (j - e0)] = buf[j];
  }
}

__global__ __launch_bounds__(256) void bbuild_kernel(
    const int* __restrict__ bases, const int* __restrict__ BC,
    const uint2* __restrict__ binned, int* __restrict__ rs,
    int* __restrict__ csr_src, int n) {
  __shared__ int nd[256], sc[256], cur[256];
  const int b = blockIdx.x;
  const int t = threadIdx.x;
  const int base = bases[b];
  const int count = BC[b];
  const int node0 = b << BSHIFT;

  nd[t] = 0;
  __syncthreads();
  for (int i = t; i < count; i += 256)
    atomicAdd(&nd[binned[base + i].x & 255], 1);
  __syncthreads();

  sc[t] = nd[t];
  __syncthreads();
  for (int st = 1; st < 256; st <<= 1) {
    const int v = sc[t];
    const int u = (t >= st) ? sc[t - st] : 0;
    __syncthreads();
    sc[t] = v + u;
    __syncthreads();
  }
  const int excl = sc[t] - nd[t];
  cur[t] = excl;
  if (node0 + t < n) rs[node0 + t] = base + excl;
  __syncthreads();

  for (int i = t; i < count; i += 256) {
    const uint2 p = binned[base + i];
    const int pos = atomicAdd(&cur[p.x & 255], 1);
    csr_src[base + pos] = (int)p.y;
  }
}

// ---------------- Gather v6: LDS private-copy scatter -----------------------
__global__ __launch_bounds__(256) void gather6_kernel(
    const int* __restrict__ rs, const int* __restrict__ csr_src,
    const unsigned char* __restrict__ Cs, const float* __restrict__ Vs,
    const float* __restrict__ eps_p, short* __restrict__ Ah,
    short* __restrict__ Al, int nrows) {
  __shared__ __align__(16) float sv[4][16][16];          // staged vals
  __shared__ __align__(16) unsigned char scb[4][16][16]; // staged cols
  __shared__ float accb[4][4 * 132];                     // 4 copies/wave
  const int lane = threadIdx.x & 63;
  const int wid = threadIdx.x >> 6;
  const float e1 = 1.0f + *eps_p;
  const int ee = lane >> 2;   // staging: edge slot
  const int q = lane & 3;     // staging: quarter
  const int g = lane >> 4;    // scatter: edge group 0..3
  const int p = lane & 15;    // scatter: nnz index
  float* acc = accb[wid];
  float4* acc4 = (float4*)acc;

  for (int r = blockIdx.x * 4 + wid; r < nrows; r += gridDim.x * 4) {
    for (int i = lane; i < 132; i += 64)
      acc4[i] = make_float4(0.f, 0.f, 0.f, 0.f);

    const int beg = rs[r], end = rs[r + 1];
    for (int base = beg; base < end; base += 16) {
      const int cnt = min(16, end - base);
      if (ee < cnt) {
        const int s = csr_src[base + ee];
        if (q == 0) {
          const int4 c4 = *(const int4*)&Cs[(size_t)s * 16];
          *(int4*)&scb[wid][ee][0] = c4;
        }
        const float4 v = *(const float4*)&Vs[(size_t)s * 16 + q * 4];
        *(float4*)&sv[wid][ee][q * 4] = v;
      }
      for (int e = 0; e < cnt; e += 4) {
        const int eg = e + g;
        if (eg < cnt) {
          const int col = scb[wid][eg][p];
          const float val = sv[wid][eg][p];
          acc[g * 132 + col] += val;
        }
      }
    }
    if (lane < 16) {
      const int c = Cs[(size_t)r * 16 + lane];
      const float v = Vs[(size_t)r * 16 + lane];
      acc[c] += e1 * v;
    }
    const float a0 = acc[lane] + acc[132 + lane] + acc[264 + lane] +
                     acc[396 + lane];
    const float a1 = acc[64 + lane] + acc[132 + 64 + lane] +
                     acc[264 + 64 + lane] + acc[396 + 64 + lane];
    const unsigned h0 = rne_bf16(a0);
    const unsigned h1 = rne_bf16(a1);
    Ah[(size_t)r * 128 + lane] = (short)h0;
    Ah[(size_t)r * 128 + 64 + lane] = (short)h1;
    Al[(size_t)r * 128 + lane] =
        (short)rne_bf16(a0 - __uint_as_float(h0 << 16));
    Al[(size_t)r * 128 + 64 + lane] =
        (short)rne_bf16(a1 - __uint_as_float(h1 << 16));
  }
}

// ---------------------------------------------------------------------------
extern "C" void kernel_launch(void* const* d_in, const int* in_sizes, int n_in,
                              void* d_out, int out_size, void* d_ws,
                              size_t ws_size, hipStream_t stream) {
  const float* x = (const float*)d_in[0];
  const int* src = (const int*)d_in[1];
  const int* dst = (const int*)d_in[2];
  const float* W_in = (const float*)d_in[3];
  const float* b_in = (const float*)d_in[4];
  const float* W_lin = (const float*)d_in[5];
  const float* b_lin = (const float*)d_in[6];
  const float* eps = (const float*)d_in[7];
  const float* W_out = (const float*)d_in[8];
  const float* b_out = (const float*)d_in[9];
  float* out = (float*)d_out;

  const int n = in_sizes[0] / 128;
  const int E = in_sizes[1];

  char* w = (char*)d_ws;
  float* B = (float*)w;               w += (size_t)n * 128 * 4;
  unsigned char* Cs = (unsigned char*)w; w += (size_t)n * 16;
  float* Vs = (float*)w;              w += (size_t)n * 16 * 4;
  int* rs = (int*)w;                  w += (size_t)(n + 1) * 4;
  int* csr_src = (int*)w;             w += (size_t)E * 4;
  uint2* binned = (uint2*)w;          w += (size_t)E * 8;
  int* BC = (int*)w;                  w += NBUK * 4;
  int* bases = (int*)w;               w += NBUK * 4;
  int* bcur = (int*)w;                w += NBUK * 4;
  short* wtAll = (short*)w;           w += (size_t)114688 * 2;
  short* Ah = (short*)w;              w += (size_t)n * 128 * 2;
  short* Al = (short*)w;              w += (size_t)n * 128 * 2;

  short* wtIn = wtAll;
  short* wtL0 = wtAll + 32768;
  short* wtL1 = wtAll + 65536;
  short* wtOut = wtAll + 98304;

  const int ptiles = (n + 255) / 256;      // 256-row tiles (all GEMMs)
  const int nbuk_eff = (n + 255) >> BSHIFT;
  const int chunk = 4000;
  const int cblocks = (E + chunk - 1) / chunk;
  const dim3 blk(256);

  // ---- CSR build ----
  hipMemsetAsync(BC, 0, NBUK * 4, stream);
  bhist_kernel<<<256, blk, 0, stream>>>(dst, BC, E);
  bscan_kernel<<<1, NBUK, 0, stream>>>(BC, bases, bcur, rs, n, E);
  bin_kernel<<<cblocks, blk, 0, stream>>>(src, dst, bcur, binned, E, chunk);
  bbuild_kernel<<<nbuk_eff, blk, 0, stream>>>(bases, BC, binned, rs, csr_src,
                                              n);

  // ---- weights -> hi/lo bf16 ----
  wt_build_all_kernel<<<(57344 + 255) / 256, blk, 0, stream>>>(W_in, W_lin,
                                                               W_out, wtAll);

  // ---- h = relu(x @ W_in + b_in) -> planes ----
  gemm_in_kernel<<<ptiles, blk, 0, stream>>>(x, wtIn, wtIn + 16384, b_in, Ah,
                                             Al, n, ptiles);

  for (int l = 0; l < 2; ++l) {
    short* wt = l ? wtL1 : wtL0;
    gemm_pl_kernel<128><<<ptiles, blk, 0, stream>>>(
        Ah, Al, wt, wt + 16384, b_lin + (size_t)l * 128, B, n, ptiles);
    maxk_kernel<<<2048, blk, 0, stream>>>(B, Cs, Vs, n);
    gather6_kernel<<<2048, blk, 0, stream>>>(rs, csr_src, Cs, Vs, eps + l, Ah,
                                             Al, n);
  }

  gemm_pl_kernel<64><<<ptiles, blk, 0, stream>>>(Ah, Al, wtOut, wtOut + 8192,
                                                 b_out, out, n, ptiles);
}

// Round 19
// 425.425 us; speedup vs baseline: 1.0803x; 1.0803x over previous
//
#include <hip/hip_runtime.h>
#include <cstdint>
#include <cstddef>

// ---------------------------------------------------------------------------
// MaxKGIN. R19: revert r18 (lo-from-L2 refetch-bound, 460us). Base = r15
// (394us, full-LDS W). A/B on the last GEMM occupancy lever: 512-thr blocks
// (8 waves share one 69.6KB W stage -> 16 waves/CU, but 6 MFMA/fragment vs
// 12). layer0 = 256-thr gemm_pl (proven), layer1 = 512-thr gemm_pl8.
// maxk v3, gather6, CSR two-level binning frozen.
// ---------------------------------------------------------------------------

typedef __attribute__((ext_vector_type(8))) short bf16x8;
typedef __attribute__((ext_vector_type(4))) float f32x4;

#define BSHIFT 8
#define NBUK 512  // covers dst>>8 for n <= 131072

__device__ __forceinline__ unsigned rne_bf16(float v) {
  unsigned u = __float_as_uint(v);
  return (u + 0x7fffu + ((u >> 16) & 1u)) >> 16;
}

// ---------------- fused W^T build: all 4 weights -> hi/lo bf16 --------------
__global__ __launch_bounds__(256) void wt_build_all_kernel(
    const float* __restrict__ W_in, const float* __restrict__ W_lin,
    const float* __restrict__ W_out, short* __restrict__ out) {
  const int i = blockIdx.x * 256 + threadIdx.x;
  if (i >= 57344) return;
  const float* W;
  int nout, local;
  short* H;
  if (i < 16384) {
    W = W_in; nout = 128; local = i; H = out;
  } else if (i < 32768) {
    W = W_lin; nout = 128; local = i - 16384; H = out + 32768;
  } else if (i < 49152) {
    W = W_lin + 16384; nout = 128; local = i - 32768; H = out + 65536;
  } else {
    W = W_out; nout = 64; local = i - 49152; H = out + 98304;
  }
  const int nn = local >> 7, k = local & 127;
  const float v = W[k * nout + nn];
  const unsigned hb = rne_bf16(v);
  const float hf = __uint_as_float(hb << 16);
  const unsigned lb = rne_bf16(v - hf);
  H[local] = (short)hb;
  H[local + nout * 128] = (short)lb;
}

// ---------------- GEMM A (fp32 X): 256-row tiles, 4 rowgroups/wave ----------
__global__ __launch_bounds__(256, 2) void gemm_in_kernel(
    const float* __restrict__ X, const short* __restrict__ WtH,
    const short* __restrict__ WtL, const float* __restrict__ bias,
    short* __restrict__ Yh, short* __restrict__ Yl, int nrows, int ntiles) {
  constexpr int NOUT = 128;
  constexpr int NT = NOUT / 16;
  constexpr int LDB = 128 * 2 + 16;
  constexpr int PLANE = NOUT * LDB;
  __shared__ char lds[2 * PLANE];

  const int tid = threadIdx.x;
  for (int u = tid; u < 2 * NOUT * 16; u += 256) {
    const int plane = u / (NOUT * 16);
    const int v = u % (NOUT * 16);
    const int nrow = v >> 4, seg = v & 15;
    const short* src = plane ? WtL : WtH;
    const float4 d = *(const float4*)&src[nrow * 128 + seg * 8];
    *(float4*)&lds[plane * PLANE + nrow * LDB + seg * 16] = d;
  }
  __syncthreads();

  const int lane = tid & 63;
  const int wv = tid >> 6;
  const int li = lane & 15;
  const int kg = lane >> 4;

  float bv[NT];
#pragma unroll
  for (int t = 0; t < NT; ++t) bv[t] = bias[t * 16 + li];

  for (int tile = blockIdx.x; tile < ntiles; tile += gridDim.x) {
    const int rowbase = tile * 256 + wv * 64;

    f32x4 acc[4][NT];
#pragma unroll
    for (int rg = 0; rg < 4; ++rg)
#pragma unroll
      for (int t = 0; t < NT; ++t) acc[rg][t] = (f32x4){0.f, 0.f, 0.f, 0.f};

#pragma unroll
    for (int c = 0; c < 4; ++c) {
      bf16x8 ah[4], al[4];
#pragma unroll
      for (int rg = 0; rg < 4; ++rg) {
        const int row = rowbase + rg * 16 + li;
        const int rowc = (row < nrows) ? row : (nrows - 1);
        const float* xrow = X + (size_t)rowc * 128 + c * 32 + kg * 8;
        const float4 p0 = *(const float4*)&xrow[0];
        const float4 p1 = *(const float4*)&xrow[4];
        const float f[8] = {p0.x, p0.y, p0.z, p0.w, p1.x, p1.y, p1.z, p1.w};
#pragma unroll
        for (int e = 0; e < 8; ++e) {
          const unsigned hb = rne_bf16(f[e]);
          const float hf = __uint_as_float(hb << 16);
          ah[rg][e] = (short)hb;
          al[rg][e] = (short)rne_bf16(f[e] - hf);
        }
      }
      const int kb = c * 64 + kg * 16;
#pragma unroll
      for (int t = 0; t < NT; ++t) {
        const bf16x8 bh = *(const bf16x8*)&lds[(t * 16 + li) * LDB + kb];
        const bf16x8 bl = *(const bf16x8*)&lds[PLANE + (t * 16 + li) * LDB + kb];
#pragma unroll
        for (int rg = 0; rg < 4; ++rg) {
          acc[rg][t] =
              __builtin_amdgcn_mfma_f32_16x16x32_bf16(al[rg], bh, acc[rg][t], 0, 0, 0);
          acc[rg][t] =
              __builtin_amdgcn_mfma_f32_16x16x32_bf16(ah[rg], bl, acc[rg][t], 0, 0, 0);
          acc[rg][t] =
              __builtin_amdgcn_mfma_f32_16x16x32_bf16(ah[rg], bh, acc[rg][t], 0, 0, 0);
        }
      }
    }

#pragma unroll
    for (int rg = 0; rg < 4; ++rg) {
      const int orow = rowbase + rg * 16 + kg * 4;
#pragma unroll
      for (int t = 0; t < NT; ++t) {
        const int col = t * 16 + li;
#pragma unroll
        for (int r = 0; r < 4; ++r) {
          const int rr = orow + r;
          if (rr < nrows) {
            const float o = fmaxf(acc[rg][t][r] + bv[t], 0.f);
            const unsigned hb = rne_bf16(o);
            const float hf = __uint_as_float(hb << 16);
            Yh[(size_t)rr * 128 + col] = (short)hb;
            Yl[(size_t)rr * 128 + col] = (short)rne_bf16(o - hf);
          }
        }
      }
    }
  }
}

// ---------------- GEMM B (bf16-plane X): 256-thr, 4 rowgroups/wave ----------
template <int NOUT>
__global__ __launch_bounds__(256, 2) void gemm_pl_kernel(
    const short* __restrict__ Xh, const short* __restrict__ Xl,
    const short* __restrict__ WtH, const short* __restrict__ WtL,
    const float* __restrict__ bias, float* __restrict__ Y, int nrows,
    int ntiles) {
  constexpr int NT = NOUT / 16;
  constexpr int LDB = 128 * 2 + 16;
  constexpr int PLANE = NOUT * LDB;
  __shared__ char lds[2 * PLANE];

  const int tid = threadIdx.x;
  for (int u = tid; u < 2 * NOUT * 16; u += 256) {
    const int plane = u / (NOUT * 16);
    const int v = u % (NOUT * 16);
    const int nrow = v >> 4, seg = v & 15;
    const short* src = plane ? WtL : WtH;
    const float4 d = *(const float4*)&src[nrow * 128 + seg * 8];
    *(float4*)&lds[plane * PLANE + nrow * LDB + seg * 16] = d;
  }
  __syncthreads();

  const int lane = tid & 63;
  const int wv = tid >> 6;
  const int li = lane & 15;
  const int kg = lane >> 4;

  float bv[NT];
#pragma unroll
  for (int t = 0; t < NT; ++t) bv[t] = bias[t * 16 + li];

  for (int tile = blockIdx.x; tile < ntiles; tile += gridDim.x) {
    const int rowbase = tile * 256 + wv * 64;

    f32x4 acc[4][NT];
#pragma unroll
    for (int rg = 0; rg < 4; ++rg)
#pragma unroll
      for (int t = 0; t < NT; ++t) acc[rg][t] = (f32x4){0.f, 0.f, 0.f, 0.f};

#pragma unroll
    for (int c = 0; c < 4; ++c) {
      bf16x8 ah[4], al[4];
#pragma unroll
      for (int rg = 0; rg < 4; ++rg) {
        const int row = rowbase + rg * 16 + li;
        const int rowc = (row < nrows) ? row : (nrows - 1);
        ah[rg] = *(const bf16x8*)&Xh[(size_t)rowc * 128 + c * 32 + kg * 8];
        al[rg] = *(const bf16x8*)&Xl[(size_t)rowc * 128 + c * 32 + kg * 8];
      }
      const int kb = c * 64 + kg * 16;
#pragma unroll
      for (int t = 0; t < NT; ++t) {
        const bf16x8 bh = *(const bf16x8*)&lds[(t * 16 + li) * LDB + kb];
        const bf16x8 bl = *(const bf16x8*)&lds[PLANE + (t * 16 + li) * LDB + kb];
#pragma unroll
        for (int rg = 0; rg < 4; ++rg) {
          acc[rg][t] =
              __builtin_amdgcn_mfma_f32_16x16x32_bf16(al[rg], bh, acc[rg][t], 0, 0, 0);
          acc[rg][t] =
              __builtin_amdgcn_mfma_f32_16x16x32_bf16(ah[rg], bl, acc[rg][t], 0, 0, 0);
          acc[rg][t] =
              __builtin_amdgcn_mfma_f32_16x16x32_bf16(ah[rg], bh, acc[rg][t], 0, 0, 0);
        }
      }
    }

#pragma unroll
    for (int rg = 0; rg < 4; ++rg) {
      const int orow = rowbase + rg * 16 + kg * 4;
#pragma unroll
      for (int t = 0; t < NT; ++t) {
        const int col = t * 16 + li;
#pragma unroll
        for (int r = 0; r < 4; ++r) {
          const int rr = orow + r;
          if (rr < nrows) Y[(size_t)rr * NOUT + col] = acc[rg][t][r] + bv[t];
        }
      }
    }
  }
}

// ---------------- GEMM B8 (bf16-plane X): 512-thr, 2 rowgroups/wave ---------
// 8 waves share one W stage: 2 blocks/CU -> 16 waves/CU (vs 8).
__global__ __launch_bounds__(512, 2) void gemm_pl8_kernel(
    const short* __restrict__ Xh, const short* __restrict__ Xl,
    const short* __restrict__ WtH, const short* __restrict__ WtL,
    const float* __restrict__ bias, float* __restrict__ Y, int nrows,
    int ntiles) {
  constexpr int NOUT = 128;
  constexpr int NT = NOUT / 16;
  constexpr int LDB = 128 * 2 + 16;
  constexpr int PLANE = NOUT * LDB;
  __shared__ char lds[2 * PLANE];

  const int tid = threadIdx.x;
  for (int u = tid; u < 2 * NOUT * 16; u += 512) {
    const int plane = u / (NOUT * 16);
    const int v = u % (NOUT * 16);
    const int nrow = v >> 4, seg = v & 15;
    const short* src = plane ? WtL : WtH;
    const float4 d = *(const float4*)&src[nrow * 128 + seg * 8];
    *(float4*)&lds[plane * PLANE + nrow * LDB + seg * 16] = d;
  }
  __syncthreads();

  const int lane = tid & 63;
  const int wv = tid >> 6;  // 0..7
  const int li = lane & 15;
  const int kg = lane >> 4;

  float bv[NT];
#pragma unroll
  for (int t = 0; t < NT; ++t) bv[t] = bias[t * 16 + li];

  for (int tile = blockIdx.x; tile < ntiles; tile += gridDim.x) {
    const int rowbase = tile * 256 + wv * 32;

    f32x4 acc[2][NT];
#pragma unroll
    for (int rg = 0; rg < 2; ++rg)
#pragma unroll
      for (int t = 0; t < NT; ++t) acc[rg][t] = (f32x4){0.f, 0.f, 0.f, 0.f};

#pragma unroll
    for (int c = 0; c < 4; ++c) {
      bf16x8 ah[2], al[2];
#pragma unroll
      for (int rg = 0; rg < 2; ++rg) {
        const int row = rowbase + rg * 16 + li;
        const int rowc = (row < nrows) ? row : (nrows - 1);
        ah[rg] = *(const bf16x8*)&Xh[(size_t)rowc * 128 + c * 32 + kg * 8];
        al[rg] = *(const bf16x8*)&Xl[(size_t)rowc * 128 + c * 32 + kg * 8];
      }
      const int kb = c * 64 + kg * 16;
#pragma unroll
      for (int t = 0; t < NT; ++t) {
        const bf16x8 bh = *(const bf16x8*)&lds[(t * 16 + li) * LDB + kb];
        const bf16x8 bl = *(const bf16x8*)&lds[PLANE + (t * 16 + li) * LDB + kb];
#pragma unroll
        for (int rg = 0; rg < 2; ++rg) {
          acc[rg][t] =
              __builtin_amdgcn_mfma_f32_16x16x32_bf16(al[rg], bh, acc[rg][t], 0, 0, 0);
          acc[rg][t] =
              __builtin_amdgcn_mfma_f32_16x16x32_bf16(ah[rg], bl, acc[rg][t], 0, 0, 0);
          acc[rg][t] =
              __builtin_amdgcn_mfma_f32_16x16x32_bf16(ah[rg], bh, acc[rg][t], 0, 0, 0);
        }
      }
    }

#pragma unroll
    for (int rg = 0; rg < 2; ++rg) {
      const int orow = rowbase + rg * 16 + kg * 4;
#pragma unroll
      for (int t = 0; t < NT; ++t) {
        const int col = t * 16 + li;
#pragma unroll
        for (int r = 0; r < 4; ++r) {
          const int rr = orow + r;
          if (rr < nrows) Y[(size_t)rr * NOUT + col] = acc[rg][t][r] + bv[t];
        }
      }
    }
  }
}

// ---------------- MaxK v3: 4 rows/wave, subgroup radix + early exit ---------
__global__ __launch_bounds__(256) void maxk_kernel(
    const float* __restrict__ T, unsigned char* __restrict__ Cs,
    float* __restrict__ Vs, int nrows) {
  const int lane = threadIdx.x & 63;
  const int wid = threadIdx.x >> 6;
  const int sub = lane >> 4;
  const int s = lane & 15;
  const int shift = sub * 16;
  const unsigned below = (1u << s) - 1u;
  const int nquads = (nrows + 3) / 4;

  for (int quad = blockIdx.x * 4 + wid; quad < nquads; quad += gridDim.x * 4) {
    const int row = quad * 4 + sub;
    const int rowc = (row < nrows) ? row : (nrows - 1);
    const float* Trow = T + (size_t)rowc * 128;

    float v[8];
    unsigned k[8];
#pragma unroll
    for (int j = 0; j < 8; ++j) {
      v[j] = Trow[j * 16 + s];
      const unsigned u = __float_as_uint(v[j]);
      k[j] = u ^ (((unsigned)((int)u >> 31)) | 0x80000000u);
    }

    unsigned P = 0;
    int kth = 16;
    int sz = 128;
    bool done = false;
    for (int b = 31; b >= 0; --b) {
      const unsigned tgt = (P >> b) | 1u;
      int c = 0;
#pragma unroll
      for (int j = 0; j < 8; ++j) {
        const unsigned long long bal = __ballot((k[j] >> b) == tgt);
        c += __popc((unsigned)((bal >> shift) & 0xFFFFull));
      }
      if (!done) {
        if (c >= kth) {
          P |= (1u << b);
          sz = c;
        } else {
          sz -= c;
          kth -= c;
        }
        done = (sz == kth);
      }
      if (__all(done)) break;
    }
    if (done) P -= 1u;  // select key >= old P; no ties remain

    unsigned gtm[8], eqm[8];
    int gt_total = 0;
#pragma unroll
    for (int j = 0; j < 8; ++j) {
      const unsigned long long gb = __ballot(k[j] > P);
      const unsigned long long eb = __ballot(k[j] == P);
      gtm[j] = (unsigned)((gb >> shift) & 0xFFFFull);
      eqm[j] = (unsigned)((eb >> shift) & 0xFFFFull);
      gt_total += __popc(gtm[j]);
    }
    const int need = 16 - gt_total;
    int gt_pre = 0, eq_pre = 0;
#pragma unroll
    for (int j = 0; j < 8; ++j) {
      const bool isgt = k[j] > P;
      const bool iseq = k[j] == P;
      const int gtb = gt_pre + __popc(gtm[j] & below);
      const int eqb = eq_pre + __popc(eqm[j] & below);
      if (row < nrows && (isgt || (iseq && eqb < need))) {
        const int rank = gtb + (isgt ? min(eqb, need) : eqb);
        Vs[(size_t)row * 16 + rank] = v[j];
        Cs[(size_t)row * 16 + rank] = (unsigned char)(j * 16 + s);
      }
      gt_pre += __popc(gtm[j]);
      eq_pre += __popc(eqm[j]);
    }
  }
}

// ---------------- CSR build v2: two-level binning ---------------------------
__global__ __launch_bounds__(256) void bhist_kernel(const int* __restrict__ dst,
                                                    int* __restrict__ BC,
                                                    int E) {
  __shared__ int bh[NBUK];
  for (int i = threadIdx.x; i < NBUK; i += 256) bh[i] = 0;
  __syncthreads();
  const int stride = gridDim.x * 256;
  for (int e = blockIdx.x * 256 + threadIdx.x; e < E; e += stride)
    atomicAdd(&bh[dst[e] >> BSHIFT], 1);
  __syncthreads();
  for (int i = threadIdx.x; i < NBUK; i += 256)
    if (bh[i]) atomicAdd(&BC[i], bh[i]);
}

__global__ __launch_bounds__(NBUK) void bscan_kernel(
    const int* __restrict__ BC, int* __restrict__ bases,
    int* __restrict__ bcur, int* __restrict__ rs, int n, int E) {
  __shared__ int sc[NBUK];
  const int t = threadIdx.x;
  const int c = BC[t];
  sc[t] = c;
  __syncthreads();
  for (int st = 1; st < NBUK; st <<= 1) {
    const int v = sc[t];
    const int u = (t >= st) ? sc[t - st] : 0;
    __syncthreads();
    sc[t] = v + u;
    __syncthreads();
  }
  const int excl = sc[t] - c;
  bases[t] = excl;
  bcur[t] = excl;
  if (t == 0) rs[n] = E;
}

__global__ __launch_bounds__(256) void bin_kernel(
    const int* __restrict__ src, const int* __restrict__ dst,
    int* __restrict__ bcur, uint2* __restrict__ binned, int E, int chunk) {
  __shared__ int cnt[NBUK], off[NBUK], gbase[NBUK];
  __shared__ unsigned short bktof[4096];
  __shared__ uint2 buf[4096];
  const int t = threadIdx.x;
  const int beg = blockIdx.x * chunk;
  const int m = min(chunk, E - beg);
  if (m <= 0) return;

  for (int i = t; i < NBUK; i += 256) cnt[i] = 0;
  __syncthreads();

  int d[16], s[16], lp[16], bk[16];
#pragma unroll
  for (int i = 0; i < 16; ++i) {
    const int j = i * 256 + t;
    if (j < m) {
      d[i] = dst[beg + j];
      s[i] = src[beg + j];
      bk[i] = d[i] >> BSHIFT;
      lp[i] = atomicAdd(&cnt[bk[i]], 1);
    } else {
      bk[i] = -1;
    }
  }
  __syncthreads();

  for (int i = t; i < NBUK; i += 256) off[i] = cnt[i];
  __syncthreads();
  for (int st = 1; st < NBUK; st <<= 1) {
    int v0, v1, u0, u1;
    {
      const int i0 = t, i1 = t + 256;
      v0 = off[i0]; u0 = (i0 >= st) ? off[i0 - st] : 0;
      v1 = off[i1]; u1 = (i1 >= st) ? off[i1 - st] : 0;
    }
    __syncthreads();
    off[t] = v0 + u0;
    off[t + 256] = v1 + u1;
    __syncthreads();
  }

  for (int i = t; i < NBUK; i += 256) {
    const int c = cnt[i];
    if (c > 0) {
      gbase[i] = atomicAdd(&bcur[i], c);
      const int e0 = off[i] - c;
      for (int k = 0; k < c; ++k) bktof[e0 + k] = (unsigned short)i;
    }
  }
  __syncthreads();

#pragma unroll
  for (int i = 0; i < 16; ++i) {
    if (bk[i] >= 0) {
      buf[(off[bk[i]] - cnt[bk[i]]) + lp[i]] =
          make_uint2((unsigned)d[i], (unsigned)s[i]);
    }
  }
  __syncthreads();

  for (int j = t; j < m; j += 256) {
    const int b = bktof[j];
    const int e0 = off[b] - cnt[b];
    binned[gbase[b] + (j - e0)] = buf[j];
  }
}

__global__ __launch_bounds__(256) void bbuild_kernel(
    const int* __restrict__ bases, const int* __restrict__ BC,
    const uint2* __restrict__ binned, int* __restrict__ rs,
    int* __restrict__ csr_src, int n) {
  __shared__ int nd[256], sc[256], cur[256];
  const int b = blockIdx.x;
  const int t = threadIdx.x;
  const int base = bases[b];
  const int count = BC[b];
  const int node0 = b << BSHIFT;

  nd[t] = 0;
  __syncthreads();
  for (int i = t; i < count; i += 256)
    atomicAdd(&nd[binned[base + i].x & 255], 1);
  __syncthreads();

  sc[t] = nd[t];
  __syncthreads();
  for (int st = 1; st < 256; st <<= 1) {
    const int v = sc[t];
    const int u = (t >= st) ? sc[t - st] : 0;
    __syncthreads();
    sc[t] = v + u;
    __syncthreads();
  }
  const int excl = sc[t] - nd[t];
  cur[t] = excl;
  if (node0 + t < n) rs[node0 + t] = base + excl;
  __syncthreads();

  for (int i = t; i < count; i += 256) {
    const uint2 p = binned[base + i];
    const int pos = atomicAdd(&cur[p.x & 255], 1);
    csr_src[base + pos] = (int)p.y;
  }
}

// ---------------- Gather v6: LDS private-copy scatter -----------------------
__global__ __launch_bounds__(256) void gather6_kernel(
    const int* __restrict__ rs, const int* __restrict__ csr_src,
    const unsigned char* __restrict__ Cs, const float* __restrict__ Vs,
    const float* __restrict__ eps_p, short* __restrict__ Ah,
    short* __restrict__ Al, int nrows) {
  __shared__ __align__(16) float sv[4][16][16];          // staged vals
  __shared__ __align__(16) unsigned char scb[4][16][16]; // staged cols
  __shared__ float accb[4][4 * 132];                     // 4 copies/wave
  const int lane = threadIdx.x & 63;
  const int wid = threadIdx.x >> 6;
  const float e1 = 1.0f + *eps_p;
  const int ee = lane >> 2;   // staging: edge slot
  const int q = lane & 3;     // staging: quarter
  const int g = lane >> 4;    // scatter: edge group 0..3
  const int p = lane & 15;    // scatter: nnz index
  float* acc = accb[wid];
  float4* acc4 = (float4*)acc;

  for (int r = blockIdx.x * 4 + wid; r < nrows; r += gridDim.x * 4) {
    for (int i = lane; i < 132; i += 64)
      acc4[i] = make_float4(0.f, 0.f, 0.f, 0.f);

    const int beg = rs[r], end = rs[r + 1];
    for (int base = beg; base < end; base += 16) {
      const int cnt = min(16, end - base);
      if (ee < cnt) {
        const int s = csr_src[base + ee];
        if (q == 0) {
          const int4 c4 = *(const int4*)&Cs[(size_t)s * 16];
          *(int4*)&scb[wid][ee][0] = c4;
        }
        const float4 v = *(const float4*)&Vs[(size_t)s * 16 + q * 4];
        *(float4*)&sv[wid][ee][q * 4] = v;
      }
      for (int e = 0; e < cnt; e += 4) {
        const int eg = e + g;
        if (eg < cnt) {
          const int col = scb[wid][eg][p];
          const float val = sv[wid][eg][p];
          acc[g * 132 + col] += val;
        }
      }
    }
    if (lane < 16) {
      const int c = Cs[(size_t)r * 16 + lane];
      const float v = Vs[(size_t)r * 16 + lane];
      acc[c] += e1 * v;
    }
    const float a0 = acc[lane] + acc[132 + lane] + acc[264 + lane] +
                     acc[396 + lane];
    const float a1 = acc[64 + lane] + acc[132 + 64 + lane] +
                     acc[264 + 64 + lane] + acc[396 + 64 + lane];
    const unsigned h0 = rne_bf16(a0);
    const unsigned h1 = rne_bf16(a1);
    Ah[(size_t)r * 128 + lane] = (short)h0;
    Ah[(size_t)r * 128 + 64 + lane] = (short)h1;
    Al[(size_t)r * 128 + lane] =
        (short)rne_bf16(a0 - __uint_as_float(h0 << 16));
    Al[(size_t)r * 128 + 64 + lane] =
        (short)rne_bf16(a1 - __uint_as_float(h1 << 16));
  }
}

// ---------------------------------------------------------------------------
extern "C" void kernel_launch(void* const* d_in, const int* in_sizes, int n_in,
                              void* d_out, int out_size, void* d_ws,
                              size_t ws_size, hipStream_t stream) {
  const float* x = (const float*)d_in[0];
  const int* src = (const int*)d_in[1];
  const int* dst = (const int*)d_in[2];
  const float* W_in = (const float*)d_in[3];
  const float* b_in = (const float*)d_in[4];
  const float* W_lin = (const float*)d_in[5];
  const float* b_lin = (const float*)d_in[6];
  const float* eps = (const float*)d_in[7];
  const float* W_out = (const float*)d_in[8];
  const float* b_out = (const float*)d_in[9];
  float* out = (float*)d_out;

  const int n = in_sizes[0] / 128;
  const int E = in_sizes[1];

  char* w = (char*)d_ws;
  float* B = (float*)w;               w += (size_t)n * 128 * 4;
  unsigned char* Cs = (unsigned char*)w; w += (size_t)n * 16;
  float* Vs = (float*)w;              w += (size_t)n * 16 * 4;
  int* rs = (int*)w;                  w += (size_t)(n + 1) * 4;
  int* csr_src = (int*)w;             w += (size_t)E * 4;
  uint2* binned = (uint2*)w;          w += (size_t)E * 8;
  int* BC = (int*)w;                  w += NBUK * 4;
  int* bases = (int*)w;               w += NBUK * 4;
  int* bcur = (int*)w;                w += NBUK * 4;
  short* wtAll = (short*)w;           w += (size_t)114688 * 2;
  short* Ah = (short*)w;              w += (size_t)n * 128 * 2;
  short* Al = (short*)w;              w += (size_t)n * 128 * 2;

  short* wtIn = wtAll;
  short* wtL0 = wtAll + 32768;
  short* wtL1 = wtAll + 65536;
  short* wtOut = wtAll + 98304;

  const int ptiles = (n + 255) / 256;      // 256-row tiles (all GEMMs)
  const int nbuk_eff = (n + 255) >> BSHIFT;
  const int chunk = 4000;
  const int cblocks = (E + chunk - 1) / chunk;
  const dim3 blk(256);

  // ---- CSR build ----
  hipMemsetAsync(BC, 0, NBUK * 4, stream);
  bhist_kernel<<<256, blk, 0, stream>>>(dst, BC, E);
  bscan_kernel<<<1, NBUK, 0, stream>>>(BC, bases, bcur, rs, n, E);
  bin_kernel<<<cblocks, blk, 0, stream>>>(src, dst, bcur, binned, E, chunk);
  bbuild_kernel<<<nbuk_eff, blk, 0, stream>>>(bases, BC, binned, rs, csr_src,
                                              n);

  // ---- weights -> hi/lo bf16 ----
  wt_build_all_kernel<<<(57344 + 255) / 256, blk, 0, stream>>>(W_in, W_lin,
                                                               W_out, wtAll);

  // ---- h = relu(x @ W_in + b_in) -> planes ----
  gemm_in_kernel<<<ptiles, blk, 0, stream>>>(x, wtIn, wtIn + 16384, b_in, Ah,
                                             Al, n, ptiles);

  for (int l = 0; l < 2; ++l) {
    short* wt = l ? wtL1 : wtL0;
    if (l == 0) {
      gemm_pl_kernel<128><<<ptiles, blk, 0, stream>>>(
          Ah, Al, wt, wt + 16384, b_lin, B, n, ptiles);
    } else {
      // A/B arm: 512-thread 8-wave variant (16 waves/CU)
      gemm_pl8_kernel<<<ptiles, dim3(512), 0, stream>>>(
          Ah, Al, wt, wt + 16384, b_lin + 128, B, n, ptiles);
    }
    maxk_kernel<<<2048, blk, 0, stream>>>(B, Cs, Vs, n);
    gather6_kernel<<<2048, blk, 0, stream>>>(rs, csr_src, Cs, Vs, eps + l, Ah,
                                             Al, n);
  }

  gemm_pl_kernel<64><<<ptiles, blk, 0, stream>>>(Ah, Al, wtOut, wtOut + 8192,
                                                 b_out, out, n, ptiles);
}

// Round 20
// 385.885 us; speedup vs baseline: 1.1910x; 1.1025x over previous
//
#include <hip/hip_runtime.h>
#include <cstdint>
#include <cstddef>

// ---------------------------------------------------------------------------
// MaxKGIN. R20: A/B verdict — 512-thr GEMM loses (70-80us vs 45, 4x bank
// conflicts); GEMM search closed at 256-thr/4-rowgroup/full-LDS (r15).
// maxk v4: lane owns CONTIGUOUS cols s*8..s*8+7 -> 2x float4 loads (was 8
// scalar dwords) + loop-invariant cross-lane rank base. Radix rounds and
// selection-set logic identical to v3 (passed); slot order change is
// downstream-irrelevant (gather6 pairs are unordered).
// gather6, CSR two-level binning, gemm_in/gemm_pl frozen from r15 (394us).
// ---------------------------------------------------------------------------

typedef __attribute__((ext_vector_type(8))) short bf16x8;
typedef __attribute__((ext_vector_type(4))) float f32x4;

#define BSHIFT 8
#define NBUK 512  // covers dst>>8 for n <= 131072

__device__ __forceinline__ unsigned rne_bf16(float v) {
  unsigned u = __float_as_uint(v);
  return (u + 0x7fffu + ((u >> 16) & 1u)) >> 16;
}

// ---------------- fused W^T build: all 4 weights -> hi/lo bf16 --------------
__global__ __launch_bounds__(256) void wt_build_all_kernel(
    const float* __restrict__ W_in, const float* __restrict__ W_lin,
    const float* __restrict__ W_out, short* __restrict__ out) {
  const int i = blockIdx.x * 256 + threadIdx.x;
  if (i >= 57344) return;
  const float* W;
  int nout, local;
  short* H;
  if (i < 16384) {
    W = W_in; nout = 128; local = i; H = out;
  } else if (i < 32768) {
    W = W_lin; nout = 128; local = i - 16384; H = out + 32768;
  } else if (i < 49152) {
    W = W_lin + 16384; nout = 128; local = i - 32768; H = out + 65536;
  } else {
    W = W_out; nout = 64; local = i - 49152; H = out + 98304;
  }
  const int nn = local >> 7, k = local & 127;
  const float v = W[k * nout + nn];
  const unsigned hb = rne_bf16(v);
  const float hf = __uint_as_float(hb << 16);
  const unsigned lb = rne_bf16(v - hf);
  H[local] = (short)hb;
  H[local + nout * 128] = (short)lb;
}

// ---------------- GEMM A (fp32 X): 256-row tiles, 4 rowgroups/wave ----------
__global__ __launch_bounds__(256, 2) void gemm_in_kernel(
    const float* __restrict__ X, const short* __restrict__ WtH,
    const short* __restrict__ WtL, const float* __restrict__ bias,
    short* __restrict__ Yh, short* __restrict__ Yl, int nrows, int ntiles) {
  constexpr int NOUT = 128;
  constexpr int NT = NOUT / 16;
  constexpr int LDB = 128 * 2 + 16;
  constexpr int PLANE = NOUT * LDB;
  __shared__ char lds[2 * PLANE];

  const int tid = threadIdx.x;
  for (int u = tid; u < 2 * NOUT * 16; u += 256) {
    const int plane = u / (NOUT * 16);
    const int v = u % (NOUT * 16);
    const int nrow = v >> 4, seg = v & 15;
    const short* src = plane ? WtL : WtH;
    const float4 d = *(const float4*)&src[nrow * 128 + seg * 8];
    *(float4*)&lds[plane * PLANE + nrow * LDB + seg * 16] = d;
  }
  __syncthreads();

  const int lane = tid & 63;
  const int wv = tid >> 6;
  const int li = lane & 15;
  const int kg = lane >> 4;

  float bv[NT];
#pragma unroll
  for (int t = 0; t < NT; ++t) bv[t] = bias[t * 16 + li];

  for (int tile = blockIdx.x; tile < ntiles; tile += gridDim.x) {
    const int rowbase = tile * 256 + wv * 64;

    f32x4 acc[4][NT];
#pragma unroll
    for (int rg = 0; rg < 4; ++rg)
#pragma unroll
      for (int t = 0; t < NT; ++t) acc[rg][t] = (f32x4){0.f, 0.f, 0.f, 0.f};

#pragma unroll
    for (int c = 0; c < 4; ++c) {
      bf16x8 ah[4], al[4];
#pragma unroll
      for (int rg = 0; rg < 4; ++rg) {
        const int row = rowbase + rg * 16 + li;
        const int rowc = (row < nrows) ? row : (nrows - 1);
        const float* xrow = X + (size_t)rowc * 128 + c * 32 + kg * 8;
        const float4 p0 = *(const float4*)&xrow[0];
        const float4 p1 = *(const float4*)&xrow[4];
        const float f[8] = {p0.x, p0.y, p0.z, p0.w, p1.x, p1.y, p1.z, p1.w};
#pragma unroll
        for (int e = 0; e < 8; ++e) {
          const unsigned hb = rne_bf16(f[e]);
          const float hf = __uint_as_float(hb << 16);
          ah[rg][e] = (short)hb;
          al[rg][e] = (short)rne_bf16(f[e] - hf);
        }
      }
      const int kb = c * 64 + kg * 16;
#pragma unroll
      for (int t = 0; t < NT; ++t) {
        const bf16x8 bh = *(const bf16x8*)&lds[(t * 16 + li) * LDB + kb];
        const bf16x8 bl = *(const bf16x8*)&lds[PLANE + (t * 16 + li) * LDB + kb];
#pragma unroll
        for (int rg = 0; rg < 4; ++rg) {
          acc[rg][t] =
              __builtin_amdgcn_mfma_f32_16x16x32_bf16(al[rg], bh, acc[rg][t], 0, 0, 0);
          acc[rg][t] =
              __builtin_amdgcn_mfma_f32_16x16x32_bf16(ah[rg], bl, acc[rg][t], 0, 0, 0);
          acc[rg][t] =
              __builtin_amdgcn_mfma_f32_16x16x32_bf16(ah[rg], bh, acc[rg][t], 0, 0, 0);
        }
      }
    }

#pragma unroll
    for (int rg = 0; rg < 4; ++rg) {
      const int orow = rowbase + rg * 16 + kg * 4;
#pragma unroll
      for (int t = 0; t < NT; ++t) {
        const int col = t * 16 + li;
#pragma unroll
        for (int r = 0; r < 4; ++r) {
          const int rr = orow + r;
          if (rr < nrows) {
            const float o = fmaxf(acc[rg][t][r] + bv[t], 0.f);
            const unsigned hb = rne_bf16(o);
            const float hf = __uint_as_float(hb << 16);
            Yh[(size_t)rr * 128 + col] = (short)hb;
            Yl[(size_t)rr * 128 + col] = (short)rne_bf16(o - hf);
          }
        }
      }
    }
  }
}

// ---------------- GEMM B (bf16-plane X): 256-thr, 4 rowgroups/wave ----------
template <int NOUT>
__global__ __launch_bounds__(256, 2) void gemm_pl_kernel(
    const short* __restrict__ Xh, const short* __restrict__ Xl,
    const short* __restrict__ WtH, const short* __restrict__ WtL,
    const float* __restrict__ bias, float* __restrict__ Y, int nrows,
    int ntiles) {
  constexpr int NT = NOUT / 16;
  constexpr int LDB = 128 * 2 + 16;
  constexpr int PLANE = NOUT * LDB;
  __shared__ char lds[2 * PLANE];

  const int tid = threadIdx.x;
  for (int u = tid; u < 2 * NOUT * 16; u += 256) {
    const int plane = u / (NOUT * 16);
    const int v = u % (NOUT * 16);
    const int nrow = v >> 4, seg = v & 15;
    const short* src = plane ? WtL : WtH;
    const float4 d = *(const float4*)&src[nrow * 128 + seg * 8];
    *(float4*)&lds[plane * PLANE + nrow * LDB + seg * 16] = d;
  }
  __syncthreads();

  const int lane = tid & 63;
  const int wv = tid >> 6;
  const int li = lane & 15;
  const int kg = lane >> 4;

  float bv[NT];
#pragma unroll
  for (int t = 0; t < NT; ++t) bv[t] = bias[t * 16 + li];

  for (int tile = blockIdx.x; tile < ntiles; tile += gridDim.x) {
    const int rowbase = tile * 256 + wv * 64;

    f32x4 acc[4][NT];
#pragma unroll
    for (int rg = 0; rg < 4; ++rg)
#pragma unroll
      for (int t = 0; t < NT; ++t) acc[rg][t] = (f32x4){0.f, 0.f, 0.f, 0.f};

#pragma unroll
    for (int c = 0; c < 4; ++c) {
      bf16x8 ah[4], al[4];
#pragma unroll
      for (int rg = 0; rg < 4; ++rg) {
        const int row = rowbase + rg * 16 + li;
        const int rowc = (row < nrows) ? row : (nrows - 1);
        ah[rg] = *(const bf16x8*)&Xh[(size_t)rowc * 128 + c * 32 + kg * 8];
        al[rg] = *(const bf16x8*)&Xl[(size_t)rowc * 128 + c * 32 + kg * 8];
      }
      const int kb = c * 64 + kg * 16;
#pragma unroll
      for (int t = 0; t < NT; ++t) {
        const bf16x8 bh = *(const bf16x8*)&lds[(t * 16 + li) * LDB + kb];
        const bf16x8 bl = *(const bf16x8*)&lds[PLANE + (t * 16 + li) * LDB + kb];
#pragma unroll
        for (int rg = 0; rg < 4; ++rg) {
          acc[rg][t] =
              __builtin_amdgcn_mfma_f32_16x16x32_bf16(al[rg], bh, acc[rg][t], 0, 0, 0);
          acc[rg][t] =
              __builtin_amdgcn_mfma_f32_16x16x32_bf16(ah[rg], bl, acc[rg][t], 0, 0, 0);
          acc[rg][t] =
              __builtin_amdgcn_mfma_f32_16x16x32_bf16(ah[rg], bh, acc[rg][t], 0, 0, 0);
        }
      }
    }

#pragma unroll
    for (int rg = 0; rg < 4; ++rg) {
      const int orow = rowbase + rg * 16 + kg * 4;
#pragma unroll
      for (int t = 0; t < NT; ++t) {
        const int col = t * 16 + li;
#pragma unroll
        for (int r = 0; r < 4; ++r) {
          const int rr = orow + r;
          if (rr < nrows) Y[(size_t)rr * NOUT + col] = acc[rg][t][r] + bv[t];
        }
      }
    }
  }
}

// ---------------- MaxK v4: contiguous-col layout, 2x float4 loads -----------
// lane=(sub,s): subgroup sub owns row quad*4+sub; lane s holds cols
// s*8..s*8+7 (two float4 loads). Radix rounds identical to v3. Rank =
// (#gt before in col order) + min(#eq before, need); cross-lane bases are
// loop-invariant. Output slot order differs from v3 but downstream treats
// (Cs,Vs) as unordered pairs.
__global__ __launch_bounds__(256) void maxk_kernel(
    const float* __restrict__ T, unsigned char* __restrict__ Cs,
    float* __restrict__ Vs, int nrows) {
  const int lane = threadIdx.x & 63;
  const int wid = threadIdx.x >> 6;
  const int sub = lane >> 4;
  const int s = lane & 15;
  const int shift = sub * 16;
  const unsigned below = (1u << s) - 1u;
  const int nquads = (nrows + 3) / 4;

  for (int quad = blockIdx.x * 4 + wid; quad < nquads; quad += gridDim.x * 4) {
    const int row = quad * 4 + sub;
    const int rowc = (row < nrows) ? row : (nrows - 1);
    const float* Trow = T + (size_t)rowc * 128;

    const float4 pa = *(const float4*)&Trow[s * 8];
    const float4 pb = *(const float4*)&Trow[s * 8 + 4];
    const float v[8] = {pa.x, pa.y, pa.z, pa.w, pb.x, pb.y, pb.z, pb.w};
    unsigned k[8];
#pragma unroll
    for (int j = 0; j < 8; ++j) {
      const unsigned u = __float_as_uint(v[j]);
      k[j] = u ^ (((unsigned)((int)u >> 31)) | 0x80000000u);
    }

    unsigned P = 0;
    int kth = 16;
    int sz = 128;
    bool done = false;
    for (int b = 31; b >= 0; --b) {
      const unsigned tgt = (P >> b) | 1u;
      int c = 0;
#pragma unroll
      for (int j = 0; j < 8; ++j) {
        const unsigned long long bal = __ballot((k[j] >> b) == tgt);
        c += __popc((unsigned)((bal >> shift) & 0xFFFFull));
      }
      if (!done) {
        if (c >= kth) {
          P |= (1u << b);
          sz = c;
        } else {
          sz -= c;
          kth -= c;
        }
        done = (sz == kth);
      }
      if (__all(done)) break;
    }
    if (done) P -= 1u;  // select key >= old P; no ties remain

    unsigned gtm[8], eqm[8];
    int gt_total = 0;
#pragma unroll
    for (int j = 0; j < 8; ++j) {
      const unsigned long long gb = __ballot(k[j] > P);
      const unsigned long long eb = __ballot(k[j] == P);
      gtm[j] = (unsigned)((gb >> shift) & 0xFFFFull);
      eqm[j] = (unsigned)((eb >> shift) & 0xFFFFull);
      gt_total += __popc(gtm[j]);
    }
    const int need = 16 - gt_total;
    // cross-lane bases (cols of lanes < s all precede ours) — loop-invariant
    int gt_base = 0, eq_base = 0;
#pragma unroll
    for (int j = 0; j < 8; ++j) {
      gt_base += __popc(gtm[j] & below);
      eq_base += __popc(eqm[j] & below);
    }
    int own_gt = 0, own_eq = 0;
#pragma unroll
    for (int j = 0; j < 8; ++j) {
      const bool isgt = k[j] > P;
      const bool iseq = k[j] == P;
      const int gt_before = gt_base + own_gt;
      const int eq_before = eq_base + own_eq;
      if (row < nrows && (isgt || (iseq && eq_before < need))) {
        const int rank = gt_before + min(eq_before, need);
        Vs[(size_t)row * 16 + rank] = v[j];
        Cs[(size_t)row * 16 + rank] = (unsigned char)(s * 8 + j);
      }
      own_gt += isgt ? 1 : 0;
      own_eq += iseq ? 1 : 0;
    }
  }
}

// ---------------- CSR build v2: two-level binning ---------------------------
__global__ __launch_bounds__(256) void bhist_kernel(const int* __restrict__ dst,
                                                    int* __restrict__ BC,
                                                    int E) {
  __shared__ int bh[NBUK];
  for (int i = threadIdx.x; i < NBUK; i += 256) bh[i] = 0;
  __syncthreads();
  const int stride = gridDim.x * 256;
  for (int e = blockIdx.x * 256 + threadIdx.x; e < E; e += stride)
    atomicAdd(&bh[dst[e] >> BSHIFT], 1);
  __syncthreads();
  for (int i = threadIdx.x; i < NBUK; i += 256)
    if (bh[i]) atomicAdd(&BC[i], bh[i]);
}

__global__ __launch_bounds__(NBUK) void bscan_kernel(
    const int* __restrict__ BC, int* __restrict__ bases,
    int* __restrict__ bcur, int* __restrict__ rs, int n, int E) {
  __shared__ int sc[NBUK];
  const int t = threadIdx.x;
  const int c = BC[t];
  sc[t] = c;
  __syncthreads();
  for (int st = 1; st < NBUK; st <<= 1) {
    const int v = sc[t];
    const int u = (t >= st) ? sc[t - st] : 0;
    __syncthreads();
    sc[t] = v + u;
    __syncthreads();
  }
  const int excl = sc[t] - c;
  bases[t] = excl;
  bcur[t] = excl;
  if (t == 0) rs[n] = E;
}

__global__ __launch_bounds__(256) void bin_kernel(
    const int* __restrict__ src, const int* __restrict__ dst,
    int* __restrict__ bcur, uint2* __restrict__ binned, int E, int chunk) {
  __shared__ int cnt[NBUK], off[NBUK], gbase[NBUK];
  __shared__ unsigned short bktof[4096];
  __shared__ uint2 buf[4096];
  const int t = threadIdx.x;
  const int beg = blockIdx.x * chunk;
  const int m = min(chunk, E - beg);
  if (m <= 0) return;

  for (int i = t; i < NBUK; i += 256) cnt[i] = 0;
  __syncthreads();

  int d[16], s[16], lp[16], bk[16];
#pragma unroll
  for (int i = 0; i < 16; ++i) {
    const int j = i * 256 + t;
    if (j < m) {
      d[i] = dst[beg + j];
      s[i] = src[beg + j];
      bk[i] = d[i] >> BSHIFT;
      lp[i] = atomicAdd(&cnt[bk[i]], 1);
    } else {
      bk[i] = -1;
    }
  }
  __syncthreads();

  for (int i = t; i < NBUK; i += 256) off[i] = cnt[i];
  __syncthreads();
  for (int st = 1; st < NBUK; st <<= 1) {
    int v0, v1, u0, u1;
    {
      const int i0 = t, i1 = t + 256;
      v0 = off[i0]; u0 = (i0 >= st) ? off[i0 - st] : 0;
      v1 = off[i1]; u1 = (i1 >= st) ? off[i1 - st] : 0;
    }
    __syncthreads();
    off[t] = v0 + u0;
    off[t + 256] = v1 + u1;
    __syncthreads();
  }

  for (int i = t; i < NBUK; i += 256) {
    const int c = cnt[i];
    if (c > 0) {
      gbase[i] = atomicAdd(&bcur[i], c);
      const int e0 = off[i] - c;
      for (int k = 0; k < c; ++k) bktof[e0 + k] = (unsigned short)i;
    }
  }
  __syncthreads();

#pragma unroll
  for (int i = 0; i < 16; ++i) {
    if (bk[i] >= 0) {
      buf[(off[bk[i]] - cnt[bk[i]]) + lp[i]] =
          make_uint2((unsigned)d[i], (unsigned)s[i]);
    }
  }
  __syncthreads();

  for (int j = t; j < m; j += 256) {
    const int b = bktof[j];
    const int e0 = off[b] - cnt[b];
    binned[gbase[b] + (j - e0)] = buf[j];
  }
}

__global__ __launch_bounds__(256) void bbuild_kernel(
    const int* __restrict__ bases, const int* __restrict__ BC,
    const uint2* __restrict__ binned, int* __restrict__ rs,
    int* __restrict__ csr_src, int n) {
  __shared__ int nd[256], sc[256], cur[256];
  const int b = blockIdx.x;
  const int t = threadIdx.x;
  const int base = bases[b];
  const int count = BC[b];
  const int node0 = b << BSHIFT;

  nd[t] = 0;
  __syncthreads();
  for (int i = t; i < count; i += 256)
    atomicAdd(&nd[binned[base + i].x & 255], 1);
  __syncthreads();

  sc[t] = nd[t];
  __syncthreads();
  for (int st = 1; st < 256; st <<= 1) {
    const int v = sc[t];
    const int u = (t >= st) ? sc[t - st] : 0;
    __syncthreads();
    sc[t] = v + u;
    __syncthreads();
  }
  const int excl = sc[t] - nd[t];
  cur[t] = excl;
  if (node0 + t < n) rs[node0 + t] = base + excl;
  __syncthreads();

  for (int i = t; i < count; i += 256) {
    const uint2 p = binned[base + i];
    const int pos = atomicAdd(&cur[p.x & 255], 1);
    csr_src[base + pos] = (int)p.y;
  }
}

// ---------------- Gather v6: LDS private-copy scatter -----------------------
__global__ __launch_bounds__(256) void gather6_kernel(
    const int* __restrict__ rs, const int* __restrict__ csr_src,
    const unsigned char* __restrict__ Cs, const float* __restrict__ Vs,
    const float* __restrict__ eps_p, short* __restrict__ Ah,
    short* __restrict__ Al, int nrows) {
  __shared__ __align__(16) float sv[4][16][16];          // staged vals
  __shared__ __align__(16) unsigned char scb[4][16][16]; // staged cols
  __shared__ float accb[4][4 * 132];                     // 4 copies/wave
  const int lane = threadIdx.x & 63;
  const int wid = threadIdx.x >> 6;
  const float e1 = 1.0f + *eps_p;
  const int ee = lane >> 2;   // staging: edge slot
  const int q = lane & 3;     // staging: quarter
  const int g = lane >> 4;    // scatter: edge group 0..3
  const int p = lane & 15;    // scatter: nnz index
  float* acc = accb[wid];
  float4* acc4 = (float4*)acc;

  for (int r = blockIdx.x * 4 + wid; r < nrows; r += gridDim.x * 4) {
    for (int i = lane; i < 132; i += 64)
      acc4[i] = make_float4(0.f, 0.f, 0.f, 0.f);

    const int beg = rs[r], end = rs[r + 1];
    for (int base = beg; base < end; base += 16) {
      const int cnt = min(16, end - base);
      if (ee < cnt) {
        const int s = csr_src[base + ee];
        if (q == 0) {
          const int4 c4 = *(const int4*)&Cs[(size_t)s * 16];
          *(int4*)&scb[wid][ee][0] = c4;
        }
        const float4 v = *(const float4*)&Vs[(size_t)s * 16 + q * 4];
        *(float4*)&sv[wid][ee][q * 4] = v;
      }
      for (int e = 0; e < cnt; e += 4) {
        const int eg = e + g;
        if (eg < cnt) {
          const int col = scb[wid][eg][p];
          const float val = sv[wid][eg][p];
          acc[g * 132 + col] += val;
        }
      }
    }
    if (lane < 16) {
      const int c = Cs[(size_t)r * 16 + lane];
      const float v = Vs[(size_t)r * 16 + lane];
      acc[c] += e1 * v;
    }
    const float a0 = acc[lane] + acc[132 + lane] + acc[264 + lane] +
                     acc[396 + lane];
    const float a1 = acc[64 + lane] + acc[132 + 64 + lane] +
                     acc[264 + 64 + lane] + acc[396 + 64 + lane];
    const unsigned h0 = rne_bf16(a0);
    const unsigned h1 = rne_bf16(a1);
    Ah[(size_t)r * 128 + lane] = (short)h0;
    Ah[(size_t)r * 128 + 64 + lane] = (short)h1;
    Al[(size_t)r * 128 + lane] =
        (short)rne_bf16(a0 - __uint_as_float(h0 << 16));
    Al[(size_t)r * 128 + 64 + lane] =
        (short)rne_bf16(a1 - __uint_as_float(h1 << 16));
  }
}

// ---------------------------------------------------------------------------
extern "C" void kernel_launch(void* const* d_in, const int* in_sizes, int n_in,
                              void* d_out, int out_size, void* d_ws,
                              size_t ws_size, hipStream_t stream) {
  const float* x = (const float*)d_in[0];
  const int* src = (const int*)d_in[1];
  const int* dst = (const int*)d_in[2];
  const float* W_in = (const float*)d_in[3];
  const float* b_in = (const float*)d_in[4];
  const float* W_lin = (const float*)d_in[5];
  const float* b_lin = (const float*)d_in[6];
  const float* eps = (const float*)d_in[7];
  const float* W_out = (const float*)d_in[8];
  const float* b_out = (const float*)d_in[9];
  float* out = (float*)d_out;

  const int n = in_sizes[0] / 128;
  const int E = in_sizes[1];

  char* w = (char*)d_ws;
  float* B = (float*)w;               w += (size_t)n * 128 * 4;
  unsigned char* Cs = (unsigned char*)w; w += (size_t)n * 16;
  float* Vs = (float*)w;              w += (size_t)n * 16 * 4;
  int* rs = (int*)w;                  w += (size_t)(n + 1) * 4;
  int* csr_src = (int*)w;             w += (size_t)E * 4;
  uint2* binned = (uint2*)w;          w += (size_t)E * 8;
  int* BC = (int*)w;                  w += NBUK * 4;
  int* bases = (int*)w;               w += NBUK * 4;
  int* bcur = (int*)w;                w += NBUK * 4;
  short* wtAll = (short*)w;           w += (size_t)114688 * 2;
  short* Ah = (short*)w;              w += (size_t)n * 128 * 2;
  short* Al = (short*)w;              w += (size_t)n * 128 * 2;

  short* wtIn = wtAll;
  short* wtL0 = wtAll + 32768;
  short* wtL1 = wtAll + 65536;
  short* wtOut = wtAll + 98304;

  const int ptiles = (n + 255) / 256;      // 256-row tiles (all GEMMs)
  const int nbuk_eff = (n + 255) >> BSHIFT;
  const int chunk = 4000;
  const int cblocks = (E + chunk - 1) / chunk;
  const dim3 blk(256);

  // ---- CSR build ----
  hipMemsetAsync(BC, 0, NBUK * 4, stream);
  bhist_kernel<<<256, blk, 0, stream>>>(dst, BC, E);
  bscan_kernel<<<1, NBUK, 0, stream>>>(BC, bases, bcur, rs, n, E);
  bin_kernel<<<cblocks, blk, 0, stream>>>(src, dst, bcur, binned, E, chunk);
  bbuild_kernel<<<nbuk_eff, blk, 0, stream>>>(bases, BC, binned, rs, csr_src,
                                              n);

  // ---- weights -> hi/lo bf16 ----
  wt_build_all_kernel<<<(57344 + 255) / 256, blk, 0, stream>>>(W_in, W_lin,
                                                               W_out, wtAll);

  // ---- h = relu(x @ W_in + b_in) -> planes ----
  gemm_in_kernel<<<ptiles, blk, 0, stream>>>(x, wtIn, wtIn + 16384, b_in, Ah,
                                             Al, n, ptiles);

  for (int l = 0; l < 2; ++l) {
    short* wt = l ? wtL1 : wtL0;
    gemm_pl_kernel<128><<<ptiles, blk, 0, stream>>>(
        Ah, Al, wt, wt + 16384, b_lin + (size_t)l * 128, B, n, ptiles);
    maxk_kernel<<<2048, blk, 0, stream>>>(B, Cs, Vs, n);
    gather6_kernel<<<2048, blk, 0, stream>>>(rs, csr_src, Cs, Vs, eps + l, Ah,
                                             Al, n);
  }

  gemm_pl_kernel<64><<<ptiles, blk, 0, stream>>>(Ah, Al, wtOut, wtOut + 8192,
                                                 b_out, out, n, ptiles);
}